// Round 10
// baseline (344.969 us; speedup 1.0000x reference)
//
#include <hip/hip_runtime.h>

#define NTRAIN 1024
#define NY 2
#define DDIM 128
#define NB 256
#define NITER 16
#define TT 1026          // NTRAIN + NY
#define TP 1088          // orig-index padding (for p/bl/xsq arrays)
#define CP 640           // class panel size (10*64); holds up to 639 train + 1 default
#define TPP (2*CP)       // 1280 permuted slots
#define SCALE_C 0.25f
#define GAMMA_C 0.05f
#define TAU_C 256.0f     // 2*D

typedef _Float16 __attribute__((ext_vector_type(8))) f16x8;
typedef __attribute__((ext_vector_type(4))) float f32x4;
typedef __attribute__((ext_vector_type(8))) unsigned short us8;

union FR16 { ushort4 u[2]; f16x8 v; };

__device__ __forceinline__ float sigm(float x) {
    return 1.0f / (1.0f + __expf(-x));
}
__device__ __forceinline__ ushort f2u16(_Float16 h) {
    union { _Float16 h; ushort u; } x; x.h = h; return x.u;
}

// ---------------- prep: p, base_logit (orig index space) ----------------
__global__ void k_prep(const float* __restrict__ Xtr, const float* __restrict__ Xdef,
                       const float* __restrict__ worder, const float* __restrict__ wbase,
                       float* __restrict__ p, float* __restrict__ bl) {
    int t = blockIdx.x;        // 0..TP-1
    int tx = threadIdx.x;      // 128 threads
    __shared__ float sp[128], sb[128];
    float po = 0.f, bo = 0.f;
    if (t < TT) {
        const float* row = (t < NTRAIN) ? (Xtr + (size_t)t * DDIM)
                                        : (Xdef + (size_t)(t - NTRAIN) * DDIM);
        float x = row[tx];
        po = x * worder[tx];
        bo = x * wbase[tx];
    }
    sp[tx] = po; sb[tx] = bo;
    __syncthreads();
    for (int off = 64; off > 0; off >>= 1) {
        if (tx < off) { sp[tx] += sp[tx+off]; sb[tx] += sb[tx+off]; }
        __syncthreads();
    }
    if (tx == 0) { p[t] = sp[0]; bl[t] = sb[0]; }
}

// ---------------- label-sort permutation via 64-bit ballot (Y==2) + class counts ----------------
__global__ void k_perm2(const int* __restrict__ ytr, const float* __restrict__ p,
                        int* __restrict__ map, float* __restrict__ pp, int* __restrict__ nc) {
    __shared__ int cnt1[16];
    int tid = threadIdx.x;                 // 1024 threads = 16 waves
    int w = tid >> 6, lane = tid & 63;
    for (int a = tid; a < TPP; a += 1024) map[a] = -1;
    int y = ytr[tid];
    unsigned long long b1 = __ballot(y == 1);
    if (lane == 0) cnt1[w] = (int)__popcll(b1);
    __syncthreads();
    int pref1 = 0, tot1 = 0;
    #pragma unroll
    for (int ww = 0; ww < 16; ww++) { pref1 += (ww < w) ? cnt1[ww] : 0; tot1 += cnt1[ww]; }
    int pref0 = w * 64 - pref1;
    unsigned long long mlt = ((unsigned long long)1 << lane) - 1ull;
    int rank = y ? (pref1 + (int)__popcll(b1 & mlt))
                 : (pref0 + (int)__popcll((~b1) & mlt));
    if (rank < CP - 1) map[y * CP + rank] = tid;
    if (tid < NY) map[tid * CP + CP - 1] = NTRAIN + tid;
    if (tid == 0) {
        int n1 = tot1 < CP - 1 ? tot1 : CP - 1;
        int n0 = (NTRAIN - tot1) < CP - 1 ? (NTRAIN - tot1) : CP - 1;
        nc[0] = n0; nc[1] = n1;
    }
    __syncthreads();
    for (int a = tid; a < TPP; a += 1024) {
        int m = map[a];
        pp[a] = (m >= 0) ? p[m] : 0.f;
    }
}

// ---------------- qsq[m] = |Xq[m]|^2 ----------------
__global__ void k_qsq(const float* __restrict__ Xq, float* __restrict__ qsq) {
    int m = threadIdx.x;   // 256 threads, 1 block
    const float4* q4 = (const float4*)(Xq + (size_t)m * DDIM);
    float s = 0.f;
    #pragma unroll
    for (int d = 0; d < DDIM / 4; d++) {
        float4 q = q4[d];
        s = fmaf(q.x, q.x, fmaf(q.y, q.y, fmaf(q.z, q.z, fmaf(q.w, q.w, s))));
    }
    qsq[m] = s;
}

// ---------------- partial blocked product, Es computed on the fly from pp ----------------
#define KC 16
__global__ __launch_bounds__(256) void k_pblk3(const float* __restrict__ pp,
                                               const int* __restrict__ nc,
                                               float* __restrict__ P, int kspan) {
    __shared__ float Wt[KC][68];
    __shared__ float Et[KC][68];
    __shared__ float ppi[64], ppj[64], ppk[320], mka[320], mkt[320];
    int c  = blockIdx.z & 1;
    int kz = blockIdx.z >> 1;
    int i0l = blockIdx.y * 64, j0l = blockIdx.x * 64;
    int k0l = kz * kspan;                      // panel-local k base
    int tid = threadIdx.x;
    int tx = tid & 15, ty = tid >> 4;
    int ncc = nc[c], ncd = nc[1 - c];
    const float* ppc = pp + c * CP;
    const float* ppd = pp + (1 - c) * CP;
    if (tid < 64) ppi[tid] = ppc[i0l + tid];
    else if (tid < 128) ppj[tid - 64] = ppd[j0l + tid - 64];
    for (int e = tid; e < kspan; e += 256) {
        int kl = k0l + e;
        ppk[e] = ppc[kl];
        mka[e] = (kl < ncc) ? 1.f : 0.f;                    // k valid as attacker
        mkt[e] = (kl < ncc || kl == CP - 1) ? 1.f : 0.f;    // k valid as target
    }
    __syncthreads();

    float prod[4][4];
    #pragma unroll
    for (int a = 0; a < 4; a++)
        #pragma unroll
        for (int b = 0; b < 4; b++) prod[a][b] = 1.f;

    for (int kc0 = 0; kc0 < kspan; kc0 += KC) {
        __syncthreads();
        #pragma unroll
        for (int e = tid; e < KC * 64; e += 256) {   // Wt[kk][ii] = Es[i][k] masked
            int kk = e & 15, ii = e >> 4;
            float s = sigm(SCALE_C * (ppi[ii] - ppk[kc0 + kk]));
            float w = s * s * mkt[kc0 + kk];
            int il = i0l + ii, kl = k0l + kc0 + kk;
            if (il >= ncc || il == kl) w = 0.f;      // va(i), no diag
            Wt[kk][ii] = w;
        }
        #pragma unroll
        for (int e = tid; e < KC * 64; e += 256) {   // Et[kk][jj] = Es[k][j] masked
            int jj = e & 63, kk = e >> 6;
            float s = sigm(SCALE_C * (ppk[kc0 + kk] - ppj[jj]));
            float v = s * s * mka[kc0 + kk];
            int jl = j0l + jj;
            if (jl >= ncd && jl != CP - 1) v = 0.f;  // vt(j)
            Et[kk][jj] = v;
        }
        __syncthreads();
        #pragma unroll
        for (int kk = 0; kk < KC; kk++) {
            float4 wv = *(const float4*)&Wt[kk][ty * 4];
            float4 ev = *(const float4*)&Et[kk][tx * 4];
            float w[4] = {wv.x, wv.y, wv.z, wv.w};
            float e[4] = {ev.x, ev.y, ev.z, ev.w};
            #pragma unroll
            for (int a = 0; a < 4; a++)
                #pragma unroll
                for (int b = 0; b < 4; b++)
                    prod[a][b] *= fmaf(-w[a], e[b], 1.f);
        }
    }
    float* Pz = P + (size_t)blockIdx.z * CP * CP;
    int jjl = blockIdx.x * 64 + tx * 4;
    #pragma unroll
    for (int a = 0; a < 4; a++) {
        int iil = blockIdx.y * 64 + ty * 4 + a;
        *(float4*)&Pz[(size_t)iil * CP + jjl] =
            make_float4(prod[a][0], prod[a][1], prod[a][2], prod[a][3]);
    }
}

// ---------------- combine partials + assemble A' + write transposed fp16 ATF ----------------
__global__ __launch_bounds__(256) void k_afin2T(const float* __restrict__ P, int psplit,
                                                const int* __restrict__ map,
                                                const float* __restrict__ pp,
                                                ushort* __restrict__ ATF) {
    __shared__ float t[64][65];
    int n0 = blockIdx.y * 64;
    int d = (n0 >= CP) ? 1 : 0;    // panel of n (target col)
    int c = 1 - d;                 // panel of k (attacker row)
    int kl0 = blockIdx.x * 64;
    int tid = threadIdx.x;
    for (int e = tid; e < 64 * 64; e += 256) {
        int r = e >> 6, col = e & 63;            // col fast -> coalesced P reads
        int iil = kl0 + r;
        int jjl = n0 - d * CP + col;             // local col within P slab
        size_t rem = (size_t)iil * CP + jjl;
        float prod = P[(size_t)c * CP * CP + rem];
        for (int kz = 1; kz < psplit; kz++)
            prod *= P[(size_t)(kz * 2 + c) * CP * CP + rem];
        int a = c * CP + iil, b = n0 + col;
        float v = 0.f;
        int mi = map[a], mj = map[b];
        if (mi >= 0 && mi < NTRAIN && mj >= 0) {
            float E = sigm(SCALE_C * (pp[a] - pp[b]));
            v = -(E * E * prod + E * (1.f - E));   // attacks*blocked + sym
        }
        t[r][col] = v;
    }
    __syncthreads();
    for (int e = tid; e < 64 * 64; e += 256) {
        int kk = e & 63, nn = e >> 6;            // kk fast -> coalesced ushort writes
        ATF[(size_t)(n0 + nn) * CP + kl0 + kk] = f2u16((_Float16)t[kk][nn]);
    }
}

// ---------------- CT (f32) + S0 fp16; 8 queries per block staged in LDS ----------------
__global__ __launch_bounds__(256) void k_cq3(const float* __restrict__ Xtr,
                                             const float* __restrict__ Xdef,
                                             const float* __restrict__ Xq,
                                             const float* __restrict__ bl,
                                             const float* __restrict__ qsq,
                                             const int* __restrict__ map,
                                             float* __restrict__ CT, ushort* __restrict__ SF) {
    __shared__ float qv[8][132];
    int bt0 = blockIdx.x * 256, bq0 = blockIdx.y * 8;
    int tid = threadIdx.x;
    for (int e = tid; e < 8 * 128; e += 256) {
        int q = e >> 7, dd = e & 127;
        qv[q][dd] = Xq[(size_t)(bq0 + q) * DDIM + dd];
    }
    __syncthreads();
    int t = bt0 + tid;
    int mi = map[t];
    float cv[8];
    float sv = 0.f;
    #pragma unroll
    for (int q = 0; q < 8; q++) cv[q] = 0.f;
    if (mi >= 0) {
        const float* row = (mi < NTRAIN) ? (Xtr + (size_t)mi * DDIM)
                                         : (Xdef + (size_t)(mi - NTRAIN) * DDIM);
        const float4* x4 = (const float4*)row;
        float dot[8];
        #pragma unroll
        for (int q = 0; q < 8; q++) dot[q] = 0.f;
        float xs = 0.f;
        #pragma unroll 8
        for (int d4 = 0; d4 < 32; d4++) {
            float4 x = x4[d4];
            xs = fmaf(x.x, x.x, fmaf(x.y, x.y, fmaf(x.z, x.z, fmaf(x.w, x.w, xs))));
            #pragma unroll
            for (int q = 0; q < 8; q++) {
                float4 qq = *(const float4*)&qv[q][d4 * 4];   // broadcast LDS read
                dot[q] = fmaf(x.x, qq.x, fmaf(x.y, qq.y, fmaf(x.z, qq.z, fmaf(x.w, qq.w, dot[q]))));
            }
        }
        float blv = bl[mi];
        sv = sigm(blv);
        #pragma unroll
        for (int q = 0; q < 8; q++) {
            float sq = qsq[bq0 + q] + xs - 2.f * dot[q];
            cv[q] = blv - sigm(GAMMA_C * (sq - TAU_C));
        }
    }
    ushort su = f2u16((_Float16)sv);
    #pragma unroll
    for (int q = 0; q < 8; q++) {
        CT[(size_t)(bq0 + q) * TPP + t] = cv[q];   // coalesced
        SF[(size_t)(bq0 + q) * TPP + t] = su;      // coalesced
    }
}

// ---------------- MFMA A/B fragment-layout probe (exact-integer, f16) ----------------
__device__ __forceinline__ float Aval(int m, int k) { return (float)((3*m + 7*k) % 13 - 6); }
__device__ __forceinline__ float Bval(int k, int n) { return (float)((5*k + 11*n) % 9 - 4); }

__global__ void k_probe(int* __restrict__ flag) {
    int lane = threadIdx.x;        // 1 wave
    int lg = lane >> 4, li = lane & 15;
    FR16 fa, fb;
    #pragma unroll
    for (int j = 0; j < 8; j++) {
        int k = (j < 4) ? (4*lg + j) : (16 + 4*lg + (j - 4));   // hypothesis H0
        fa.v[j] = (_Float16)Aval(li, k);
        fb.v[j] = (_Float16)Bval(k, li);
    }
    f32x4 acc = {0.f, 0.f, 0.f, 0.f};
    acc = __builtin_amdgcn_mfma_f32_16x16x32_f16(fa.v, fb.v, acc, 0, 0, 0);
    int ok = 1;
    #pragma unroll
    for (int r = 0; r < 4; r++) {
        int row = 4*lg + r, col = li;
        float ref = 0.f;
        for (int k = 0; k < 32; k++) ref += Aval(row, k) * Bval(k, col);
        if (acc[r] != ref) ok = 0;
    }
    int allok = __all(ok);
    if (lane == 0) *flag = allok ? 0 : 1;   // 0 -> H0, 1 -> H1 (k = 8*lg + j)
}

// ---------------- one iteration: single-stage 121KB-LDS MFMA, 160 blocks ----------------
// grid (TPP/64=20, NB/32=8); 256 thr = 4 waves (2m x 2n); tile 32m x 64n, K=640 staged once.
__global__ __launch_bounds__(256, 1) void k_it3(const ushort* __restrict__ SF,
                                                const ushort* __restrict__ ATF,
                                                const float* __restrict__ CT,
                                                const int* __restrict__ map,
                                                const int* __restrict__ flag,
                                                ushort* __restrict__ NF,
                                                float* __restrict__ out, int last) {
    __shared__ ushort SfL[32][648];   // 32 m-rows x 640 k (+8 pad) = 40.5 KB
    __shared__ ushort AfL[64][648];   // 64 n-rows x 640 k (+8 pad) = 81 KB
    int tid = threadIdx.x;
    int n0 = blockIdx.x * 64, m0 = blockIdx.y * 32;
    int kb = (n0 >= CP) ? 0 : CP;     // k over OPPOSITE panel (global slots)
    int wv = tid >> 6, lane = tid & 63;
    int wm = wv >> 1, wn = wv & 1;
    int lg = lane >> 4, li = lane & 15;
    int hyp = *flag;
    int o0 = hyp ? (8*lg)     : (4*lg);
    int o1 = hyp ? (8*lg + 4) : (16 + 4*lg);

    for (int e = tid; e < 32 * 80; e += 256) {       // S slab, coalesced 16B
        int r = e / 80, c8 = e % 80;
        *(us8*)&SfL[r][c8 * 8] = *(const us8*)(SF + (size_t)(m0 + r) * TPP + kb + c8 * 8);
    }
    for (int e = tid; e < 64 * 80; e += 256) {       // A slab, coalesced 16B
        int r = e / 80, c8 = e % 80;
        *(us8*)&AfL[r][c8 * 8] = *(const us8*)(ATF + (size_t)(n0 + r) * CP + c8 * 8);
    }
    __syncthreads();

    f32x4 a0 = {0.f,0.f,0.f,0.f}, a1 = {0.f,0.f,0.f,0.f};
    #pragma unroll
    for (int ks = 0; ks < 20; ks++) {
        int ka = ks * 32;
        FR16 fs, f0, f1;
        fs.u[0] = *(const ushort4*)&SfL[wm * 16 + li][ka + o0];
        fs.u[1] = *(const ushort4*)&SfL[wm * 16 + li][ka + o1];
        f0.u[0] = *(const ushort4*)&AfL[wn * 32 + li][ka + o0];
        f0.u[1] = *(const ushort4*)&AfL[wn * 32 + li][ka + o1];
        f1.u[0] = *(const ushort4*)&AfL[wn * 32 + 16 + li][ka + o0];
        f1.u[1] = *(const ushort4*)&AfL[wn * 32 + 16 + li][ka + o1];
        a0 = __builtin_amdgcn_mfma_f32_16x16x32_f16(fs.v, f0.v, a0, 0, 0, 0);
        a1 = __builtin_amdgcn_mfma_f32_16x16x32_f16(fs.v, f1.v, a1, 0, 0, 0);
    }

    #pragma unroll
    for (int nt = 0; nt < 2; nt++) {
        int col = n0 + wn * 32 + nt * 16 + li;
        int valid = (map[col] >= 0);
        f32x4 ac = nt ? a1 : a0;
        #pragma unroll
        for (int r = 0; r < 4; r++) {
            int row = m0 + wm * 16 + 4 * lg + r;   // C/D: col=lane&15, row=(lane>>4)*4+reg
            float v = 0.f;
            if (valid) v = sigm(CT[(size_t)row * TPP + col] + ac[r]);
            NF[(size_t)row * TPP + col] = f2u16((_Float16)v);
            if (last && (col == CP - 1 || col == TPP - 1)) {
                int cc = (col == CP - 1) ? 0 : 1;
                out[row * NY + cc] = v;            // full-precision f32 output
            }
        }
    }
}

extern "C" void kernel_launch(void* const* d_in, const int* in_sizes, int n_in,
                              void* d_out, int out_size, void* d_ws, size_t ws_size,
                              hipStream_t stream) {
    const float* Xtr    = (const float*)d_in[0];
    const float* Xdef   = (const float*)d_in[1];
    const float* Xq     = (const float*)d_in[2];
    const float* worder = (const float*)d_in[3];
    const float* wbase  = (const float*)d_in[4];
    const int*   ytr    = (const int*)d_in[5];

    const size_t VECP = (size_t)NB * TPP * 4;      // 1.31 MB (CT)
    const size_t ATB2 = (size_t)TPP * CP * 2;      // 1.64 MB (ATF fp16)
    const size_t SB   = (size_t)NB * TPP * 2;      // 0.655 MB (SF fp16)
    auto need = [&](int ps) {
        return (size_t)(8 * 8192) + (size_t)ps * 2 * CP * CP * 4
             + ATB2 + VECP + 2 * SB + 65536;
    };
    int psplit = 8;
    if (ws_size < need(8)) psplit = 4;
    if (ws_size < need(4)) psplit = 2;
    if (ws_size < need(2)) psplit = 1;
    int kspan = CP / psplit;                       // 80/160/320 (multiples of KC, <=320)

    char* ws = (char*)d_ws;
    size_t off = 0;
    auto alloc = [&](size_t bytes) {
        void* r = ws + off;
        off += (bytes + 255) & ~(size_t)255;
        return r;
    };
    float*  p    = (float*)alloc((size_t)TP * 4);
    float*  bl   = (float*)alloc((size_t)TP * 4);
    int*    map  = (int*)  alloc((size_t)TPP * 4);
    float*  pp   = (float*)alloc((size_t)TPP * 4);
    int*    nc   = (int*)  alloc(256);
    int*    flag = (int*)  alloc(256);
    float*  qsq  = (float*)alloc((size_t)NB * 4);
    float*  P    = (float*)alloc((size_t)psplit * 2 * CP * CP * 4);
    ushort* ATF  = (ushort*)alloc(ATB2);
    float*  CT   = (float*)alloc(VECP);
    ushort* SF0  = (ushort*)alloc(SB);
    ushort* SF1  = (ushort*)alloc(SB);

    k_prep<<<TP, 128, 0, stream>>>(Xtr, Xdef, worder, wbase, p, bl);
    k_perm2<<<1, 1024, 0, stream>>>(ytr, p, map, pp, nc);
    k_qsq<<<1, 256, 0, stream>>>(Xq, qsq);
    k_cq3<<<dim3(TPP / 256, NB / 8), 256, 0, stream>>>(Xtr, Xdef, Xq, bl, qsq, map, CT, SF0);
    k_probe<<<1, 64, 0, stream>>>(flag);
    k_pblk3<<<dim3(CP / 64, CP / 64, 2 * psplit), 256, 0, stream>>>(pp, nc, P, kspan);
    k_afin2T<<<dim3(CP / 64, TPP / 64), 256, 0, stream>>>(P, psplit, map, pp, ATF);

    ushort *cf = SF0, *nf = SF1;
    for (int it = 0; it < NITER; it++) {
        k_it3<<<dim3(TPP / 64, NB / 32), 256, 0, stream>>>(cf, ATF, CT, map, flag, nf,
                                                           (float*)d_out,
                                                           it == NITER - 1 ? 1 : 0);
        ushort* t = cf; cf = nf; nf = t;
    }
}

// Round 12
// 268.412 us; speedup vs baseline: 1.2852x; 1.2852x over previous
//
#include <hip/hip_runtime.h>

#define NTRAIN 1024
#define NY 2
#define DDIM 128
#define NB 256
#define NITER 16
#define TT 1026          // NTRAIN + NY
#define TP 1088          // orig-index padding (for p/bl arrays)
#define CP 640           // class panel size (10*64); holds up to 639 train + 1 default
#define TPP (2*CP)       // 1280 permuted slots
#define SCALE_C 0.25f
#define GAMMA_C 0.05f
#define TAU_C 256.0f     // 2*D
#define IKCH 320         // k-chunk for the MFMA iteration kernel (2 chunks of K=640)

typedef _Float16 __attribute__((ext_vector_type(8))) f16x8;
typedef __attribute__((ext_vector_type(4))) float f32x4;
typedef __attribute__((ext_vector_type(8))) unsigned short us8;

union FR16 { ushort4 u[2]; f16x8 v; };

__device__ __forceinline__ float sigm(float x) {
    return 1.0f / (1.0f + __expf(-x));
}
__device__ __forceinline__ ushort f2u16(_Float16 h) {
    union { _Float16 h; ushort u; } x; x.h = h; return x.u;
}

// ---------------- prep: p, base_logit (orig index space) ----------------
__global__ void k_prep(const float* __restrict__ Xtr, const float* __restrict__ Xdef,
                       const float* __restrict__ worder, const float* __restrict__ wbase,
                       float* __restrict__ p, float* __restrict__ bl) {
    int t = blockIdx.x;        // 0..TP-1
    int tx = threadIdx.x;      // 128 threads
    __shared__ float sp[128], sb[128];
    float po = 0.f, bo = 0.f;
    if (t < TT) {
        const float* row = (t < NTRAIN) ? (Xtr + (size_t)t * DDIM)
                                        : (Xdef + (size_t)(t - NTRAIN) * DDIM);
        float x = row[tx];
        po = x * worder[tx];
        bo = x * wbase[tx];
    }
    sp[tx] = po; sb[tx] = bo;
    __syncthreads();
    for (int off = 64; off > 0; off >>= 1) {
        if (tx < off) { sp[tx] += sp[tx+off]; sb[tx] += sb[tx+off]; }
        __syncthreads();
    }
    if (tx == 0) { p[t] = sp[0]; bl[t] = sb[0]; }
}

// ---------------- label-sort permutation via 64-bit ballot (Y==2) + class counts ----------------
__global__ void k_perm2(const int* __restrict__ ytr, const float* __restrict__ p,
                        int* __restrict__ map, float* __restrict__ pp, int* __restrict__ nc) {
    __shared__ int cnt1[16];
    int tid = threadIdx.x;                 // 1024 threads = 16 waves
    int w = tid >> 6, lane = tid & 63;
    for (int a = tid; a < TPP; a += 1024) map[a] = -1;
    int y = ytr[tid];
    unsigned long long b1 = __ballot(y == 1);
    if (lane == 0) cnt1[w] = (int)__popcll(b1);
    __syncthreads();
    int pref1 = 0, tot1 = 0;
    #pragma unroll
    for (int ww = 0; ww < 16; ww++) { pref1 += (ww < w) ? cnt1[ww] : 0; tot1 += cnt1[ww]; }
    int pref0 = w * 64 - pref1;
    unsigned long long mlt = ((unsigned long long)1 << lane) - 1ull;
    int rank = y ? (pref1 + (int)__popcll(b1 & mlt))
                 : (pref0 + (int)__popcll((~b1) & mlt));
    if (rank < CP - 1) map[y * CP + rank] = tid;
    if (tid < NY) map[tid * CP + CP - 1] = NTRAIN + tid;
    if (tid == 0) {
        int n1 = tot1 < CP - 1 ? tot1 : CP - 1;
        int n0 = (NTRAIN - tot1) < CP - 1 ? (NTRAIN - tot1) : CP - 1;
        nc[0] = n0; nc[1] = n1;
    }
    __syncthreads();
    for (int a = tid; a < TPP; a += 1024) {
        int m = map[a];
        pp[a] = (m >= 0) ? p[m] : 0.f;
    }
}

// ---------------- qsq[m] = |Xq[m]|^2 ----------------
__global__ void k_qsq(const float* __restrict__ Xq, float* __restrict__ qsq) {
    int m = threadIdx.x;   // 256 threads, 1 block
    const float4* q4 = (const float4*)(Xq + (size_t)m * DDIM);
    float s = 0.f;
    #pragma unroll
    for (int d = 0; d < DDIM / 4; d++) {
        float4 q = q4[d];
        s = fmaf(q.x, q.x, fmaf(q.y, q.y, fmaf(q.z, q.z, fmaf(q.w, q.w, s))));
    }
    qsq[m] = s;
}

// ---------------- partial blocked product, Es computed on the fly from pp ----------------
#define KC 16
__global__ __launch_bounds__(256) void k_pblk3(const float* __restrict__ pp,
                                               const int* __restrict__ nc,
                                               float* __restrict__ P, int kspan) {
    __shared__ float Wt[KC][68];
    __shared__ float Et[KC][68];
    __shared__ float ppi[64], ppj[64], ppk[320], mka[320], mkt[320];
    int c  = blockIdx.z & 1;
    int kz = blockIdx.z >> 1;
    int i0l = blockIdx.y * 64, j0l = blockIdx.x * 64;
    int k0l = kz * kspan;                      // panel-local k base
    int tid = threadIdx.x;
    int tx = tid & 15, ty = tid >> 4;
    int ncc = nc[c], ncd = nc[1 - c];
    const float* ppc = pp + c * CP;
    const float* ppd = pp + (1 - c) * CP;
    if (tid < 64) ppi[tid] = ppc[i0l + tid];
    else if (tid < 128) ppj[tid - 64] = ppd[j0l + tid - 64];
    for (int e = tid; e < kspan; e += 256) {
        int kl = k0l + e;
        ppk[e] = ppc[kl];
        mka[e] = (kl < ncc) ? 1.f : 0.f;                    // k valid as attacker
        mkt[e] = (kl < ncc || kl == CP - 1) ? 1.f : 0.f;    // k valid as target
    }
    __syncthreads();

    float prod[4][4];
    #pragma unroll
    for (int a = 0; a < 4; a++)
        #pragma unroll
        for (int b = 0; b < 4; b++) prod[a][b] = 1.f;

    for (int kc0 = 0; kc0 < kspan; kc0 += KC) {
        __syncthreads();
        #pragma unroll
        for (int e = tid; e < KC * 64; e += 256) {   // Wt[kk][ii] = Es[i][k] masked
            int kk = e & 15, ii = e >> 4;
            float s = sigm(SCALE_C * (ppi[ii] - ppk[kc0 + kk]));
            float w = s * s * mkt[kc0 + kk];
            int il = i0l + ii, kl = k0l + kc0 + kk;
            if (il >= ncc || il == kl) w = 0.f;      // va(i), no diag
            Wt[kk][ii] = w;
        }
        #pragma unroll
        for (int e = tid; e < KC * 64; e += 256) {   // Et[kk][jj] = Es[k][j] masked
            int jj = e & 63, kk = e >> 6;
            float s = sigm(SCALE_C * (ppk[kc0 + kk] - ppj[jj]));
            float v = s * s * mka[kc0 + kk];
            int jl = j0l + jj;
            if (jl >= ncd && jl != CP - 1) v = 0.f;  // vt(j)
            Et[kk][jj] = v;
        }
        __syncthreads();
        #pragma unroll
        for (int kk = 0; kk < KC; kk++) {
            float4 wv = *(const float4*)&Wt[kk][ty * 4];
            float4 ev = *(const float4*)&Et[kk][tx * 4];
            float w[4] = {wv.x, wv.y, wv.z, wv.w};
            float e[4] = {ev.x, ev.y, ev.z, ev.w};
            #pragma unroll
            for (int a = 0; a < 4; a++)
                #pragma unroll
                for (int b = 0; b < 4; b++)
                    prod[a][b] *= fmaf(-w[a], e[b], 1.f);
        }
    }
    float* Pz = P + (size_t)blockIdx.z * CP * CP;
    int jjl = blockIdx.x * 64 + tx * 4;
    #pragma unroll
    for (int a = 0; a < 4; a++) {
        int iil = blockIdx.y * 64 + ty * 4 + a;
        *(float4*)&Pz[(size_t)iil * CP + jjl] =
            make_float4(prod[a][0], prod[a][1], prod[a][2], prod[a][3]);
    }
}

// ---------------- combine partials + assemble A' + write transposed fp16 ATF ----------------
__global__ __launch_bounds__(256) void k_afin2T(const float* __restrict__ P, int psplit,
                                                const int* __restrict__ map,
                                                const float* __restrict__ pp,
                                                ushort* __restrict__ ATF) {
    __shared__ float t[64][65];
    int n0 = blockIdx.y * 64;
    int d = (n0 >= CP) ? 1 : 0;    // panel of n (target col)
    int c = 1 - d;                 // panel of k (attacker row)
    int kl0 = blockIdx.x * 64;
    int tid = threadIdx.x;
    for (int e = tid; e < 64 * 64; e += 256) {
        int r = e >> 6, col = e & 63;            // col fast -> coalesced P reads
        int iil = kl0 + r;
        int jjl = n0 - d * CP + col;             // local col within P slab
        size_t rem = (size_t)iil * CP + jjl;
        float prod = P[(size_t)c * CP * CP + rem];
        for (int kz = 1; kz < psplit; kz++)
            prod *= P[(size_t)(kz * 2 + c) * CP * CP + rem];
        int a = c * CP + iil, b = n0 + col;
        float v = 0.f;
        int mi = map[a], mj = map[b];
        if (mi >= 0 && mi < NTRAIN && mj >= 0) {
            float E = sigm(SCALE_C * (pp[a] - pp[b]));
            v = -(E * E * prod + E * (1.f - E));   // attacks*blocked + sym
        }
        t[r][col] = v;
    }
    __syncthreads();
    for (int e = tid; e < 64 * 64; e += 256) {
        int kk = e & 63, nn = e >> 6;            // kk fast -> coalesced ushort writes
        ATF[(size_t)(n0 + nn) * CP + kl0 + kk] = f2u16((_Float16)t[kk][nn]);
    }
}

// ---------------- CT (f32) + S0 fp16; 8 queries per block staged in LDS ----------------
__global__ __launch_bounds__(256) void k_cq3(const float* __restrict__ Xtr,
                                             const float* __restrict__ Xdef,
                                             const float* __restrict__ Xq,
                                             const float* __restrict__ bl,
                                             const float* __restrict__ qsq,
                                             const int* __restrict__ map,
                                             float* __restrict__ CT, ushort* __restrict__ SF) {
    __shared__ float qv[8][132];
    int bt0 = blockIdx.x * 256, bq0 = blockIdx.y * 8;
    int tid = threadIdx.x;
    for (int e = tid; e < 8 * 128; e += 256) {
        int q = e >> 7, dd = e & 127;
        qv[q][dd] = Xq[(size_t)(bq0 + q) * DDIM + dd];
    }
    __syncthreads();
    int t = bt0 + tid;
    int mi = map[t];
    float cv[8];
    float sv = 0.f;
    #pragma unroll
    for (int q = 0; q < 8; q++) cv[q] = 0.f;
    if (mi >= 0) {
        const float* row = (mi < NTRAIN) ? (Xtr + (size_t)mi * DDIM)
                                         : (Xdef + (size_t)(mi - NTRAIN) * DDIM);
        const float4* x4 = (const float4*)row;
        float dot[8];
        #pragma unroll
        for (int q = 0; q < 8; q++) dot[q] = 0.f;
        float xs = 0.f;
        #pragma unroll 8
        for (int d4 = 0; d4 < 32; d4++) {
            float4 x = x4[d4];
            xs = fmaf(x.x, x.x, fmaf(x.y, x.y, fmaf(x.z, x.z, fmaf(x.w, x.w, xs))));
            #pragma unroll
            for (int q = 0; q < 8; q++) {
                float4 qq = *(const float4*)&qv[q][d4 * 4];   // broadcast LDS read
                dot[q] = fmaf(x.x, qq.x, fmaf(x.y, qq.y, fmaf(x.z, qq.z, fmaf(x.w, qq.w, dot[q]))));
            }
        }
        float blv = bl[mi];
        sv = sigm(blv);
        #pragma unroll
        for (int q = 0; q < 8; q++) {
            float sq = qsq[bq0 + q] + xs - 2.f * dot[q];
            cv[q] = blv - sigm(GAMMA_C * (sq - TAU_C));
        }
    }
    ushort su = f2u16((_Float16)sv);
    #pragma unroll
    for (int q = 0; q < 8; q++) {
        CT[(size_t)(bq0 + q) * TPP + t] = cv[q];   // coalesced
        SF[(size_t)(bq0 + q) * TPP + t] = su;      // coalesced
    }
}

// ---------------- MFMA A/B fragment-layout probe (exact-integer, f16) ----------------
__device__ __forceinline__ float Aval(int m, int k) { return (float)((3*m + 7*k) % 13 - 6); }
__device__ __forceinline__ float Bval(int k, int n) { return (float)((5*k + 11*n) % 9 - 4); }

__global__ void k_probe(int* __restrict__ flag) {
    int lane = threadIdx.x;        // 1 wave
    int lg = lane >> 4, li = lane & 15;
    FR16 fa, fb;
    #pragma unroll
    for (int j = 0; j < 8; j++) {
        int k = (j < 4) ? (4*lg + j) : (16 + 4*lg + (j - 4));   // hypothesis H0
        fa.v[j] = (_Float16)Aval(li, k);
        fb.v[j] = (_Float16)Bval(k, li);
    }
    f32x4 acc = {0.f, 0.f, 0.f, 0.f};
    acc = __builtin_amdgcn_mfma_f32_16x16x32_f16(fa.v, fb.v, acc, 0, 0, 0);
    int ok = 1;
    #pragma unroll
    for (int r = 0; r < 4; r++) {
        int row = 4*lg + r, col = li;
        float ref = 0.f;
        for (int k = 0; k < 32; k++) ref += Aval(row, k) * Bval(k, col);
        if (acc[r] != ref) ok = 0;
    }
    int allok = __all(ok);
    if (lane == 0) *flag = allok ? 0 : 1;   // 0 -> H0, 1 -> H1 (k = 8*lg + j)
}

// ---------------- one iteration: 2-chunk LDS MFMA with register prefetch ----------------
// grid (TPP/32=40, NB/32=8)=320 blocks, 256 thr = 4 waves (2m x 2n); tile 32m x 32n.
// K=640 in 2 chunks of 320; chunk-1 global loads fly under chunk-0 MFMAs (T14).
__global__ __launch_bounds__(256) void k_it4(const ushort* __restrict__ SF,
                                             const ushort* __restrict__ ATF,
                                             const float* __restrict__ CT,
                                             const int* __restrict__ map,
                                             const int* __restrict__ flag,
                                             ushort* __restrict__ NF,
                                             float* __restrict__ out, int last) {
    __shared__ ushort SfL[32][IKCH + 8];   // 21 KB
    __shared__ ushort AfL[32][IKCH + 8];   // 21 KB
    int tid = threadIdx.x;
    int n0 = blockIdx.x * 32, m0 = blockIdx.y * 32;
    int kb = (n0 >= CP) ? 0 : CP;          // k over OPPOSITE panel (global slots)
    int wv = tid >> 6, lane = tid & 63;
    int wm = wv >> 1, wn = wv & 1;
    int lg = lane >> 4, li = lane & 15;
    int hyp = *flag;
    int o0 = hyp ? (8*lg)     : (4*lg);
    int o1 = hyp ? (8*lg + 4) : (16 + 4*lg);
    int srow = tid >> 3, sc = tid & 7;     // staging: 8 threads x 5 us8 per 320-k row

    const ushort* sfg = SF + (size_t)(m0 + srow) * TPP + kb;
    const ushort* afg = ATF + (size_t)(n0 + srow) * CP;

    us8 bs[5], ba[5];
    #pragma unroll
    for (int q = 0; q < 5; q++) {
        bs[q] = *(const us8*)(sfg + sc * 8 + q * 64);
        ba[q] = *(const us8*)(afg + sc * 8 + q * 64);
    }
    #pragma unroll
    for (int q = 0; q < 5; q++) {
        *(us8*)&SfL[srow][sc * 8 + q * 64] = bs[q];
        *(us8*)&AfL[srow][sc * 8 + q * 64] = ba[q];
    }
    __syncthreads();
    // prefetch chunk 1 (latency hides under chunk-0 MFMAs)
    #pragma unroll
    for (int q = 0; q < 5; q++) {
        bs[q] = *(const us8*)(sfg + IKCH + sc * 8 + q * 64);
        ba[q] = *(const us8*)(afg + IKCH + sc * 8 + q * 64);
    }

    f32x4 c0 = {0.f,0.f,0.f,0.f};
    #pragma unroll
    for (int ks = 0; ks < IKCH / 32; ks++) {
        int ka = ks * 32;
        FR16 fs, fa;
        fs.u[0] = *(const ushort4*)&SfL[wm * 16 + li][ka + o0];
        fs.u[1] = *(const ushort4*)&SfL[wm * 16 + li][ka + o1];
        fa.u[0] = *(const ushort4*)&AfL[wn * 16 + li][ka + o0];
        fa.u[1] = *(const ushort4*)&AfL[wn * 16 + li][ka + o1];
        c0 = __builtin_amdgcn_mfma_f32_16x16x32_f16(fs.v, fa.v, c0, 0, 0, 0);
    }
    __syncthreads();                       // chunk-0 LDS reads done
    #pragma unroll
    for (int q = 0; q < 5; q++) {
        *(us8*)&SfL[srow][sc * 8 + q * 64] = bs[q];
        *(us8*)&AfL[srow][sc * 8 + q * 64] = ba[q];
    }
    __syncthreads();
    #pragma unroll
    for (int ks = 0; ks < IKCH / 32; ks++) {
        int ka = ks * 32;
        FR16 fs, fa;
        fs.u[0] = *(const ushort4*)&SfL[wm * 16 + li][ka + o0];
        fs.u[1] = *(const ushort4*)&SfL[wm * 16 + li][ka + o1];
        fa.u[0] = *(const ushort4*)&AfL[wn * 16 + li][ka + o0];
        fa.u[1] = *(const ushort4*)&AfL[wn * 16 + li][ka + o1];
        c0 = __builtin_amdgcn_mfma_f32_16x16x32_f16(fs.v, fa.v, c0, 0, 0, 0);
    }

    int col = n0 + wn * 16 + li;
    int valid = (map[col] >= 0);
    #pragma unroll
    for (int r = 0; r < 4; r++) {
        int row = m0 + wm * 16 + 4 * lg + r;   // C/D: col=lane&15, row=(lane>>4)*4+reg
        float v = 0.f;
        if (valid) v = sigm(CT[(size_t)row * TPP + col] + c0[r]);
        NF[(size_t)row * TPP + col] = f2u16((_Float16)v);
        if (last && (col == CP - 1 || col == TPP - 1)) {
            int cc = (col == CP - 1) ? 0 : 1;
            out[row * NY + cc] = v;            // full-precision f32 output
        }
    }
}

extern "C" void kernel_launch(void* const* d_in, const int* in_sizes, int n_in,
                              void* d_out, int out_size, void* d_ws, size_t ws_size,
                              hipStream_t stream) {
    const float* Xtr    = (const float*)d_in[0];
    const float* Xdef   = (const float*)d_in[1];
    const float* Xq     = (const float*)d_in[2];
    const float* worder = (const float*)d_in[3];
    const float* wbase  = (const float*)d_in[4];
    const int*   ytr    = (const int*)d_in[5];

    const size_t VECP = (size_t)NB * TPP * 4;      // 1.31 MB (CT)
    const size_t ATB2 = (size_t)TPP * CP * 2;      // 1.64 MB (ATF fp16)
    const size_t SB   = (size_t)NB * TPP * 2;      // 0.655 MB (SF fp16)
    auto need = [&](int ps) {
        return (size_t)(8 * 8192) + (size_t)ps * 2 * CP * CP * 4
             + ATB2 + VECP + 2 * SB + 65536;
    };
    int psplit = 8;
    if (ws_size < need(8)) psplit = 4;
    if (ws_size < need(4)) psplit = 2;
    if (ws_size < need(2)) psplit = 1;
    int kspan = CP / psplit;                       // 80/160/320 (multiples of KC, <=320)

    char* ws = (char*)d_ws;
    size_t off = 0;
    auto alloc = [&](size_t bytes) {
        void* r = ws + off;
        off += (bytes + 255) & ~(size_t)255;
        return r;
    };
    float*  p    = (float*)alloc((size_t)TP * 4);
    float*  bl   = (float*)alloc((size_t)TP * 4);
    int*    map  = (int*)  alloc((size_t)TPP * 4);
    float*  pp   = (float*)alloc((size_t)TPP * 4);
    int*    nc   = (int*)  alloc(256);
    int*    flag = (int*)  alloc(256);
    float*  qsq  = (float*)alloc((size_t)NB * 4);
    float*  P    = (float*)alloc((size_t)psplit * 2 * CP * CP * 4);
    ushort* ATF  = (ushort*)alloc(ATB2);
    float*  CT   = (float*)alloc(VECP);
    ushort* SF0  = (ushort*)alloc(SB);
    ushort* SF1  = (ushort*)alloc(SB);

    k_prep<<<TP, 128, 0, stream>>>(Xtr, Xdef, worder, wbase, p, bl);
    k_perm2<<<1, 1024, 0, stream>>>(ytr, p, map, pp, nc);
    k_qsq<<<1, 256, 0, stream>>>(Xq, qsq);
    k_cq3<<<dim3(TPP / 256, NB / 8), 256, 0, stream>>>(Xtr, Xdef, Xq, bl, qsq, map, CT, SF0);
    k_probe<<<1, 64, 0, stream>>>(flag);
    k_pblk3<<<dim3(CP / 64, CP / 64, 2 * psplit), 256, 0, stream>>>(pp, nc, P, kspan);
    k_afin2T<<<dim3(CP / 64, TPP / 64), 256, 0, stream>>>(P, psplit, map, pp, ATF);

    ushort *cf = SF0, *nf = SF1;
    for (int it = 0; it < NITER; it++) {
        k_it4<<<dim3(TPP / 32, NB / 32), 256, 0, stream>>>(cf, ATF, CT, map, flag, nf,
                                                           (float*)d_out,
                                                           it == NITER - 1 ? 1 : 0);
        ushort* t = cf; cf = nf; nf = t;
    }
}